// Round 12
// baseline (482.626 us; speedup 1.0000x reference)
//
#include <hip/hip_runtime.h>
#include <stdint.h>

#define B_ 8
#define S_ 2048
#define E_ 2048
#define H_ 16
#define DH_ 128
#define M_ 1024
#define K_ 2048

typedef float f32x4 __attribute__((ext_vector_type(4)));
typedef float f32x16 __attribute__((ext_vector_type(16)));
typedef __bf16 bf16x8 __attribute__((ext_vector_type(8)));
typedef unsigned short ushort8 __attribute__((ext_vector_type(8)));
typedef unsigned short ushort4v __attribute__((ext_vector_type(4)));
typedef unsigned int uint4v __attribute__((ext_vector_type(4)));
typedef float float4v __attribute__((ext_vector_type(4)));

static __device__ __forceinline__ unsigned short f2bf(float f) {
  unsigned int u = __builtin_bit_cast(unsigned int, f);
  u += 0x7fffu + ((u >> 16) & 1u);
  return (unsigned short)(u >> 16);
}

static __device__ __forceinline__ float exp2f_fast(float x) {
#if __has_builtin(__builtin_amdgcn_exp2f)
  return __builtin_amdgcn_exp2f(x);
#else
  return __expf(x * 0.6931471805599453f);
#endif
}

static __device__ __forceinline__ f32x4 mfma16(ushort8 a, ushort8 b, f32x4 c) {
  return __builtin_amdgcn_mfma_f32_16x16x32_bf16(
      __builtin_bit_cast(bf16x8, a), __builtin_bit_cast(bf16x8, b), c, 0, 0, 0);
}

static __device__ __forceinline__ f32x16 mfma32(ushort8 a, ushort8 b, f32x16 c) {
  return __builtin_amdgcn_mfma_f32_32x32x16_bf16(
      __builtin_bit_cast(bf16x8, a), __builtin_bit_cast(bf16x8, b), c, 0, 0, 0);
}

static __device__ __forceinline__ void gload_lds16(const void* g, void* l) {
  __builtin_amdgcn_global_load_lds(
      (const __attribute__((address_space(1))) unsigned int*)g,
      (__attribute__((address_space(3))) unsigned int*)l, 16, 0, 0);
}

// ---------------- conversion kernels ----------------

__global__ void cvt_bf16(const float* __restrict__ in, unsigned short* __restrict__ out, int n4) {
  int i = blockIdx.x * blockDim.x + threadIdx.x;
  int stride = gridDim.x * blockDim.x;
  for (; i < n4; i += stride) {
    float4v v = ((const float4v*)in)[i];
    ushort4v o;
    o[0] = f2bf(v[0]); o[1] = f2bf(v[1]); o[2] = f2bf(v[2]); o[3] = f2bf(v[3]);
    ((ushort4v*)out)[i] = o;
  }
}

__global__ void addcvt_bf16(const float* __restrict__ a, const float* __restrict__ b,
                            unsigned short* __restrict__ out, int n4) {
  int i = blockIdx.x * blockDim.x + threadIdx.x;
  int stride = gridDim.x * blockDim.x;
  for (; i < n4; i += stride) {
    float4v va = ((const float4v*)a)[i];
    float4v vb = ((const float4v*)b)[i];
    ushort4v o;
    o[0] = f2bf(va[0] + vb[0]); o[1] = f2bf(va[1] + vb[1]);
    o[2] = f2bf(va[2] + vb[2]); o[3] = f2bf(va[3] + vb[3]);
    ((ushort4v*)out)[i] = o;
  }
}

// batched transpose + f32->bf16: in[z][R][C] -> out[z][C][R]
__global__ __launch_bounds__(256) void transpose_cvt(const float* __restrict__ in,
                                                     unsigned short* __restrict__ out,
                                                     int R, int C) {
  __shared__ float t[64][65];
  const int tx = threadIdx.x & 63, ty = threadIdx.x >> 6;  // ty in 0..3
  const size_t base = (size_t)blockIdx.z * R * C;
  const int r0 = blockIdx.y * 64, c0 = blockIdx.x * 64;
#pragma unroll
  for (int i = 0; i < 64; i += 4)
    t[i + ty][tx] = in[base + (size_t)(r0 + i + ty) * C + (c0 + tx)];
  __syncthreads();
#pragma unroll
  for (int i = 0; i < 64; i += 4)
    out[base + (size_t)(c0 + i + ty) * R + (r0 + tx)] = f2bf(t[tx][i + ty]);
}

// ---------------- K/V fragment-order pack (for linear gload_lds staging) ----------
// KP granule i = (h, c, L): L = st*64 + g; st = mb*8+dc, g = pt*32+rw;
//   holds Kb[h][c*64 + mb*32 + rw][dc*16 + pt*8 .. +8]   (16B contiguous read)
__global__ __launch_bounds__(512) void pack_k(const unsigned short* __restrict__ Kb,
                                              unsigned short* __restrict__ KP) {
  const int i = blockIdx.x * 512 + threadIdx.x;  // 0 .. 262143
  const int L = i & 1023, c = (i >> 10) & 15, h = i >> 14;
  const int st = L >> 6, g = L & 63;
  const int mb = st >> 3, dc = st & 7, pt = g >> 5, rw = g & 31;
  const int m = c * 64 + mb * 32 + rw, d = dc * 16 + pt * 8;
  const uint4v v = *(const uint4v*)&Kb[((size_t)h * M_ + m) * DH_ + d];
  *(uint4v*)&KP[(size_t)i * 8] = v;
}

// VP granule i = (h, c, L): st = dt*4 + mb*2 + mk, g = pt*32+rw;
//   holds VT[h][dt*32 + rw][c*64 + mb*32 + mk*16 + pt*8 .. +8]
__global__ __launch_bounds__(512) void pack_v(const unsigned short* __restrict__ VT,
                                              unsigned short* __restrict__ VP) {
  const int i = blockIdx.x * 512 + threadIdx.x;
  const int L = i & 1023, c = (i >> 10) & 15, h = i >> 14;
  const int st = L >> 6, g = L & 63;
  const int dt = st >> 2, mb = (st >> 1) & 1, mk = st & 1, pt = g >> 5, rw = g & 31;
  const int d = dt * 32 + rw, m = c * 64 + mb * 32 + mk * 16 + pt * 8;
  const uint4v v = *(const uint4v*)&VT[((size_t)h * DH_ + d) * M_ + m];
  *(uint4v*)&VP[(size_t)i * 8] = v;
}

// ---------------- 8-phase pipelined GEMM ----------------
// C(16384 x 2048) = A(16384 x 2048) * BT(2048 x 2048)^T + bias.
// BM=BN=256, BK=64; 8 waves (2M x 4N); per-wave out 128x64.
template <int EPI>
__global__ __launch_bounds__(512, 2) void gemm8p(const unsigned short* __restrict__ A,
                                                 const unsigned short* __restrict__ BT,
                                                 const float* __restrict__ bias,
                                                 void* __restrict__ Cout) {
  __shared__ __align__(16) unsigned short a_lds[2][2][8192];
  __shared__ __align__(16) unsigned short b_lds[2][2][8192];
  const int tid = threadIdx.x;
  const int w = tid >> 6, lane = tid & 63;
  const int l16 = lane & 15, l4 = lane >> 4;
  const int wr = w >> 2, wc = w & 3;  // 2 x 4 wave grid
  const int bid = blockIdx.x;
  const int n0 = (bid & 7) << 8;   // XCD-pinned 1MB B slab
  const int m0 = (bid >> 3) << 8;

  const int rp0 = tid >> 3, gg0 = tid & 7, s0 = gg0 ^ (rp0 & 7);
  const int srow = rp0 * 2 + (s0 >> 2), sg = s0 & 3;
  const unsigned short* pA = A + (size_t)(m0 + srow) * K_ + sg * 8;
  const unsigned short* pB = BT + (size_t)(n0 + srow) * K_ + sg * 8;
  const int laneG = ((l16 >> 1) * 8 + (((l16 & 1) * 4 + l4) ^ ((l16 >> 1) & 7))) * 8;

  f32x4 acc[8][4];
#pragma unroll
  for (int i = 0; i < 8; ++i)
#pragma unroll
    for (int j = 0; j < 4; ++j) acc[i][j] = (f32x4)(0.f);

  ushort8 aF[4], bF[4];

#define STG(dst, srcp, T, kh)                                                \
  do {                                                                       \
    const unsigned short* s_ = (srcp) + (T) * 64 + (kh) * 32;                \
    gload_lds16(s_, &(dst)[tid * 8]);                                        \
    gload_lds16(s_ + (size_t)128 * K_, &(dst)[(512 + tid) * 8]);             \
  } while (0)

#define LDA(mg, buf, ks)                                                     \
  do {                                                                       \
    _Pragma("unroll") for (int mf = 0; mf < 4; ++mf)                         \
      aF[mf] = *(const ushort8*)&a_lds[buf][ks]                              \
          [(wr * 512 + ((mg) * 4 + mf) * 64) * 8 + laneG];                   \
  } while (0)

#define LDB(buf, ks)                                                         \
  do {                                                                       \
    _Pragma("unroll") for (int nf = 0; nf < 4; ++nf)                         \
      bF[nf] = *(const ushort8*)&b_lds[buf][ks]                              \
          [(wc * 256 + nf * 64) * 8 + laneG];                                \
  } while (0)

#define MM(mg)                                                               \
  do {                                                                       \
    __builtin_amdgcn_s_setprio(1);                                           \
    _Pragma("unroll") for (int mf = 0; mf < 4; ++mf)                         \
      _Pragma("unroll") for (int nf = 0; nf < 4; ++nf)                       \
        acc[(mg) * 4 + mf][nf] = mfma16(aF[mf], bF[nf], acc[(mg) * 4 + mf][nf]); \
    __builtin_amdgcn_s_setprio(0);                                           \
  } while (0)

#define NOVM ((void)0)
#define VMC6 asm volatile("s_waitcnt vmcnt(6)" ::: "memory")
#define VMC0 asm volatile("s_waitcnt vmcnt(0)" ::: "memory")

#define PHASE(mg, ks, buf, LOADB, STAGE, VM)                                 \
  do {                                                                       \
    if (LOADB) { LDB(buf, ks); }                                             \
    LDA(mg, buf, ks);                                                        \
    STAGE;                                                                   \
    __builtin_amdgcn_s_barrier();                                            \
    asm volatile("s_waitcnt lgkmcnt(0)" ::: "memory");                       \
    __builtin_amdgcn_sched_barrier(0);                                       \
    MM(mg);                                                                  \
    VM;                                                                      \
    __builtin_amdgcn_s_barrier();                                            \
  } while (0)

  STG(a_lds[0][0], pA, 0, 0);
  STG(b_lds[0][0], pB, 0, 0);
  STG(a_lds[0][1], pA, 0, 1);
  STG(b_lds[0][1], pB, 0, 1);
  STG(b_lds[1][0], pB, 1, 0);
  STG(a_lds[1][0], pA, 1, 0);
  STG(b_lds[1][1], pB, 1, 1);
  __builtin_amdgcn_sched_barrier(0);
  VMC6;
  __builtin_amdgcn_s_barrier();
  __builtin_amdgcn_sched_barrier(0);

#pragma unroll 1
  for (int i = 0; i < 15; ++i) {
    const int t1 = 2 * i + 1, t2 = 2 * i + 2, t3 = 2 * i + 3;
    PHASE(0, 0, 0, 1, STG(a_lds[1][1], pA, t1, 1), NOVM);
    PHASE(1, 0, 0, 0, STG(b_lds[0][0], pB, t2, 0), NOVM);
    PHASE(1, 1, 0, 1, STG(a_lds[0][0], pA, t2, 0), NOVM);
    PHASE(0, 1, 0, 0, STG(b_lds[0][1], pB, t2, 1), VMC6);
    PHASE(0, 0, 1, 1, STG(a_lds[0][1], pA, t2, 1), NOVM);
    PHASE(1, 0, 1, 0, STG(b_lds[1][0], pB, t3, 0), NOVM);
    PHASE(1, 1, 1, 1, STG(a_lds[1][0], pA, t3, 0), NOVM);
    PHASE(0, 1, 1, 0, STG(b_lds[1][1], pB, t3, 1), VMC6);
  }
  PHASE(0, 0, 0, 1, STG(a_lds[1][1], pA, 31, 1), NOVM);
  PHASE(1, 0, 0, 0, NOVM, NOVM);
  PHASE(1, 1, 0, 1, NOVM, NOVM);
  PHASE(0, 1, 0, 0, NOVM, VMC0);
  PHASE(0, 0, 1, 1, NOVM, NOVM);
  PHASE(1, 0, 1, 0, NOVM, NOVM);
  PHASE(1, 1, 1, 1, NOVM, NOVM);
  PHASE(0, 1, 1, 0, NOVM, NOVM);

#undef PHASE
#undef STG
#undef LDA
#undef LDB
#undef MM

#pragma unroll
  for (int mf = 0; mf < 8; ++mf) {
    const int mb = m0 + wr * 128 + mf * 16 + l4 * 4;
#pragma unroll
    for (int nf = 0; nf < 4; ++nf) {
      const int n = n0 + wc * 64 + nf * 16 + l16;
      const float bv = bias[n];
#pragma unroll
      for (int r = 0; r < 4; ++r) {
        const float v = acc[mf][nf][r] + bv;
        const int m = mb + r;
        if (EPI == 0) {
          const int b = m >> 11, s = m & 2047, h = n >> 7, d = n & 127;
          // pre-scale Q by log2(e)/sqrt(E) so attn uses exp2 directly
          ((unsigned short*)Cout)[(((size_t)(b * 16 + h) << 11) + s) * 128 + d] =
              f2bf(v * 0.031879358f);
        } else {
          ((float*)Cout)[(size_t)m * E_ + n] = v;
        }
      }
    }
  }
}

// ---------------- fused attention: 8 waves x 32 q-rows, packed-fragment K/V --------
// = r10 attnZ compute (refcheck-passed, 0 bank conflicts) + r6-style fully-linear
// coalesced gload_lds staging, enabled by pre-packed KP/VP (permutation moved to the
// cheap pack kernels). grid: (B*H, S/256); block 512. Swapped QK^T: col = lane&31 = s.
__global__ __launch_bounds__(512, 2) void attnP(const unsigned short* __restrict__ Qb,
                                                const unsigned short* __restrict__ KP,
                                                const unsigned short* __restrict__ VP,
                                                unsigned short* __restrict__ Ob) {
  const int bh = blockIdx.x, b = bh >> 4, h = bh & 15;
  const int tid = threadIdx.x, wv = tid >> 6, lane = tid & 63;
  const int l32 = lane & 31, hi = lane >> 5;
  const int s_glob = blockIdx.y * 256 + wv * 32 + l32;

  __shared__ __align__(16) unsigned short k_sm[2][16 * 512];  // 16 subtiles x 1KB
  __shared__ __align__(16) unsigned short v_sm[2][16 * 512];
  __shared__ float inv_lds[8][32];

  const unsigned short* KPh = KP + (size_t)h * 16 * 8192;  // per head: 16 chunks x 8192
  const unsigned short* VPh = VP + (size_t)h * 16 * 8192;

  // Q fragments (pre-scaled by log2e/sqrt(E)): B-operand col=s, k = dc*16 + hi*8 + j
  ushort8 qf[8];
  {
    const unsigned short* qrow = Qb + ((size_t)(b * 16 + h) * S_ + s_glob) * DH_ + hi * 8;
#pragma unroll
    for (int dc = 0; dc < 8; ++dc) qf[dc] = *(const ushort8*)(qrow + dc * 16);
  }

  f32x16 oacc[4];
#pragma unroll
  for (int dt = 0; dt < 4; ++dt) oacc[dt] = (f32x16)(0.f);
  float lsum = 0.f;

  // staging: fully linear — wave-instr reads 1KB contiguous from packed global, LDS
  // dst = base + lane*16B. LDS image identical to r10 attnZ (refcheck'd).
#define ASTAGE(buf, ch)                                                        \
  do {                                                                         \
    const unsigned short* kp_ = KPh + (size_t)(ch) * 8192;                     \
    const unsigned short* vp_ = VPh + (size_t)(ch) * 8192;                     \
    _Pragma("unroll") for (int j_ = 0; j_ < 2; ++j_) {                         \
      const int t_ = j_ * 512 + tid;                                           \
      gload_lds16(kp_ + t_ * 8, &k_sm[buf][t_ * 8]);                           \
      gload_lds16(vp_ + t_ * 8, &v_sm[buf][t_ * 8]);                           \
    }                                                                          \
  } while (0)

  int cur = 0;
  ASTAGE(0, 0);
  __syncthreads();

  for (int c = 0; c < 16; ++c) {
    if (c < 15) ASTAGE(cur ^ 1, c + 1);

#pragma unroll
    for (int mb = 0; mb < 2; ++mb) {
      // ---- QK^T (swapped): A = K rows (m = mb*32 + l32), B = Q cols (s) ----
      f32x16 sacc = (f32x16)(0.f);
      __builtin_amdgcn_s_setprio(1);
#pragma unroll
      for (int dc = 0; dc < 8; ++dc) {
        ushort8 kf = *(const ushort8*)&k_sm[cur][((mb * 8 + dc) * 64 + lane) * 8];
        sacc = mfma32(kf, qf[dc], sacc);
      }
      __builtin_amdgcn_s_setprio(0);

      // ---- in-register softmax (no max) + pack to PV A-frags (T12) ----
      float pe[16];
#pragma unroll
      for (int r = 0; r < 16; ++r) {
        pe[r] = exp2f_fast(sacc[r]);
        lsum += pe[r];
      }
      ushort8 pa[2];
#pragma unroll
      for (int mk = 0; mk < 2; ++mk) {
        const int o = mk * 8;
        unsigned x0, x1, y0, y1;
        asm("v_cvt_pk_bf16_f32 %0, %1, %2" : "=v"(x0) : "v"(pe[o + 0]), "v"(pe[o + 1]));
        asm("v_cvt_pk_bf16_f32 %0, %1, %2" : "=v"(x1) : "v"(pe[o + 2]), "v"(pe[o + 3]));
        asm("v_cvt_pk_bf16_f32 %0, %1, %2" : "=v"(y0) : "v"(pe[o + 4]), "v"(pe[o + 5]));
        asm("v_cvt_pk_bf16_f32 %0, %1, %2" : "=v"(y1) : "v"(pe[o + 6]), "v"(pe[o + 7]));
        asm("v_permlane32_swap_b32 %0, %1" : "+v"(x0), "+v"(y0));
        asm("v_permlane32_swap_b32 %0, %1" : "+v"(x1), "+v"(y1));
        uint4v pw;
        pw[0] = x0; pw[1] = x1; pw[2] = y0; pw[3] = y1;
        pa[mk] = __builtin_bit_cast(ushort8, pw);
      }

      // ---- PV: oacc[dt] += P(mb-range) * V ----
      __builtin_amdgcn_s_setprio(1);
#pragma unroll
      for (int dt = 0; dt < 4; ++dt) {
#pragma unroll
        for (int mk = 0; mk < 2; ++mk) {
          const int vst = dt * 4 + mb * 2 + mk;
          ushort8 vf = *(const ushort8*)&v_sm[cur][(vst * 64 + lane) * 8];
          oacc[dt] = mfma32(pa[mk], vf, oacc[dt]);
        }
      }
      __builtin_amdgcn_s_setprio(0);
    }
    __syncthreads();
    cur ^= 1;
  }
#undef ASTAGE

  // ---- epilogue: denominator, broadcast inv via LDS, store O ----
  float tot = lsum + __shfl_xor(lsum, 32, 64);
  if (hi == 0) inv_lds[wv][l32] = 1.0f / tot;
  __builtin_amdgcn_s_barrier();
#pragma unroll
  for (int r = 0; r < 16; ++r) {
    const int crow = (r & 3) + 8 * (r >> 2) + 4 * hi;
    const float iv = inv_lds[wv][crow];
    unsigned short* orow =
        Ob + ((size_t)b * S_ + (size_t)(blockIdx.y * 256 + wv * 32 + crow)) * (H_ * DH_) +
        h * DH_ + l32;
#pragma unroll
    for (int dt = 0; dt < 4; ++dt) {
      const float val = oacc[dt][r] * iv;
      unsigned u;
      asm("v_cvt_pk_bf16_f32 %0, %1, %2" : "=v"(u) : "v"(val), "v"(val));
      orow[dt * 32] = (unsigned short)u;
    }
  }
}

// ---------------- launcher ----------------

extern "C" void kernel_launch(void* const* d_in, const int* in_sizes, int n_in,
                              void* d_out, int out_size, void* d_ws, size_t ws_size,
                              hipStream_t stream) {
  const float* X   = (const float*)d_in[0];
  const float* Wq  = (const float*)d_in[1];
  const float* bq  = (const float*)d_in[2];
  const float* Kp  = (const float*)d_in[3];
  const float* Cal = (const float*)d_in[4];
  const float* V   = (const float*)d_in[5];
  const float* Wd  = (const float*)d_in[6];
  const float* bd  = (const float*)d_in[7];

  char* ws = (char*)d_ws;
  unsigned short* Xbf = (unsigned short*)(ws + 0);          // 67108864 B (reused as Ob)
  unsigned short* Ob  = Xbf;                                 // alias: X dead after GEMM1
  unsigned short* Qb  = (unsigned short*)(ws + 67108864);   // 67108864 B
  unsigned short* WqT = (unsigned short*)(ws + 134217728);  // 8388608 B
  unsigned short* WdT = (unsigned short*)(ws + 142606336);  // 8388608 B
  unsigned short* Kb  = (unsigned short*)(ws + 150994944);  // 4194304 B
  unsigned short* VT  = (unsigned short*)(ws + 155189248);  // 4194304 B
  // KP/VP overlay WqT's 8MB slot (WqT dead after GEMM1; packs run after GEMM1)
  unsigned short* KP  = (unsigned short*)(ws + 134217728);  // 4194304 B
  unsigned short* VP  = (unsigned short*)(ws + 138412032);  // 4194304 B

  // conversions
  cvt_bf16<<<2048, 256, 0, stream>>>(X, Xbf, (B_ * S_ * E_) / 4);
  addcvt_bf16<<<1024, 256, 0, stream>>>(Kp, Cal, Kb, (H_ * M_ * DH_) / 4);
  transpose_cvt<<<dim3(E_ / 64, E_ / 64, 1), 256, 0, stream>>>(Wq, WqT, E_, H_ * DH_);
  transpose_cvt<<<dim3(E_ / 64, E_ / 64, 1), 256, 0, stream>>>(Wd, WdT, H_ * DH_, E_);
  transpose_cvt<<<dim3(DH_ / 64, M_ / 64, H_), 256, 0, stream>>>(V, VT, M_, DH_);

  // Q projection: (B*S, E) x (E, H*Dh) -> Q bf16 (B,H,S,Dh), pre-scaled
  gemm8p<0><<<dim3(512), 512, 0, stream>>>(Xbf, WqT, bq, Qb);

  // pack K/V into attn fragment order (WqT slot now dead)
  pack_k<<<512, 512, 0, stream>>>(Kb, KP);
  pack_v<<<512, 512, 0, stream>>>(VT, VP);

  // fused attention -> Ob bf16 (B,S,H*Dh)
  attnP<<<dim3(B_ * H_, S_ / 256), 512, 0, stream>>>(Qb, KP, VP, Ob);

  // dehead: (B*S, H*Dh) x (H*Dh, E) -> f32 out
  gemm8p<1><<<dim3(512), 512, 0, stream>>>(Ob, WdT, bd, (float*)d_out);
}

// Round 13
// 474.821 us; speedup vs baseline: 1.0164x; 1.0164x over previous
//
#include <hip/hip_runtime.h>
#include <stdint.h>

#define B_ 8
#define S_ 2048
#define E_ 2048
#define H_ 16
#define DH_ 128
#define M_ 1024
#define K_ 2048

typedef float f32x4 __attribute__((ext_vector_type(4)));
typedef float f32x16 __attribute__((ext_vector_type(16)));
typedef __bf16 bf16x8 __attribute__((ext_vector_type(8)));
typedef unsigned short ushort8 __attribute__((ext_vector_type(8)));
typedef unsigned short ushort4v __attribute__((ext_vector_type(4)));
typedef unsigned int uint4v __attribute__((ext_vector_type(4)));
typedef float float4v __attribute__((ext_vector_type(4)));

static __device__ __forceinline__ unsigned short f2bf(float f) {
  unsigned int u = __builtin_bit_cast(unsigned int, f);
  u += 0x7fffu + ((u >> 16) & 1u);
  return (unsigned short)(u >> 16);
}

static __device__ __forceinline__ float exp2f_fast(float x) {
#if __has_builtin(__builtin_amdgcn_exp2f)
  return __builtin_amdgcn_exp2f(x);
#else
  return __expf(x * 0.6931471805599453f);
#endif
}

static __device__ __forceinline__ f32x4 mfma16(ushort8 a, ushort8 b, f32x4 c) {
  return __builtin_amdgcn_mfma_f32_16x16x32_bf16(
      __builtin_bit_cast(bf16x8, a), __builtin_bit_cast(bf16x8, b), c, 0, 0, 0);
}

static __device__ __forceinline__ f32x16 mfma32(ushort8 a, ushort8 b, f32x16 c) {
  return __builtin_amdgcn_mfma_f32_32x32x16_bf16(
      __builtin_bit_cast(bf16x8, a), __builtin_bit_cast(bf16x8, b), c, 0, 0, 0);
}

static __device__ __forceinline__ void gload_lds16(const void* g, void* l) {
  __builtin_amdgcn_global_load_lds(
      (const __attribute__((address_space(1))) unsigned int*)g,
      (__attribute__((address_space(3))) unsigned int*)l, 16, 0, 0);
}

// ---------------- conversion kernels ----------------

__global__ void cvt_bf16(const float* __restrict__ in, unsigned short* __restrict__ out, int n4) {
  int i = blockIdx.x * blockDim.x + threadIdx.x;
  int stride = gridDim.x * blockDim.x;
  for (; i < n4; i += stride) {
    float4v v = ((const float4v*)in)[i];
    ushort4v o;
    o[0] = f2bf(v[0]); o[1] = f2bf(v[1]); o[2] = f2bf(v[2]); o[3] = f2bf(v[3]);
    ((ushort4v*)out)[i] = o;
  }
}

__global__ void addcvt_bf16(const float* __restrict__ a, const float* __restrict__ b,
                            unsigned short* __restrict__ out, int n4) {
  int i = blockIdx.x * blockDim.x + threadIdx.x;
  int stride = gridDim.x * blockDim.x;
  for (; i < n4; i += stride) {
    float4v va = ((const float4v*)a)[i];
    float4v vb = ((const float4v*)b)[i];
    ushort4v o;
    o[0] = f2bf(va[0] + vb[0]); o[1] = f2bf(va[1] + vb[1]);
    o[2] = f2bf(va[2] + vb[2]); o[3] = f2bf(va[3] + vb[3]);
    ((ushort4v*)out)[i] = o;
  }
}

// batched transpose + f32->bf16: in[z][R][C] -> out[z][C][R]
__global__ __launch_bounds__(256) void transpose_cvt(const float* __restrict__ in,
                                                     unsigned short* __restrict__ out,
                                                     int R, int C) {
  __shared__ float t[64][65];
  const int tx = threadIdx.x & 63, ty = threadIdx.x >> 6;  // ty in 0..3
  const size_t base = (size_t)blockIdx.z * R * C;
  const int r0 = blockIdx.y * 64, c0 = blockIdx.x * 64;
#pragma unroll
  for (int i = 0; i < 64; i += 4)
    t[i + ty][tx] = in[base + (size_t)(r0 + i + ty) * C + (c0 + tx)];
  __syncthreads();
#pragma unroll
  for (int i = 0; i < 64; i += 4)
    out[base + (size_t)(c0 + i + ty) * R + (r0 + tx)] = f2bf(t[tx][i + ty]);
}

// ---------------- 8-phase pipelined GEMM (single barrier per phase) ----------------
// C(16384 x 2048) = A(16384 x 2048) * BT(2048 x 2048)^T + bias.
// BM=BN=256, BK=64; 8 waves (2M x 4N); per-wave out 128x64.
// Phase = {reads || stage -> lgkm(0) -> MFMA -> [vmcnt] -> barrier}. The pre-MFMA
// barrier is removed: every publish point is (VMCx + end-barrier); WAR pairs
// (stage p+1 vs reads p) keep one-barrier + ~500cy vmem-latency separation --
// same safety class as the 2-barrier schedule, but reads of wave B overlap MFMA
// of wave A (<=1 phase drift).
template <int EPI>
__global__ __launch_bounds__(512, 2) void gemm8p(const unsigned short* __restrict__ A,
                                                 const unsigned short* __restrict__ BT,
                                                 const float* __restrict__ bias,
                                                 void* __restrict__ Cout) {
  __shared__ __align__(16) unsigned short a_lds[2][2][8192];
  __shared__ __align__(16) unsigned short b_lds[2][2][8192];
  const int tid = threadIdx.x;
  const int w = tid >> 6, lane = tid & 63;
  const int l16 = lane & 15, l4 = lane >> 4;
  const int wr = w >> 2, wc = w & 3;  // 2 x 4 wave grid
  const int bid = blockIdx.x;
  const int n0 = (bid & 7) << 8;   // XCD-pinned 1MB B slab
  const int m0 = (bid >> 3) << 8;

  const int rp0 = tid >> 3, gg0 = tid & 7, s0 = gg0 ^ (rp0 & 7);
  const int srow = rp0 * 2 + (s0 >> 2), sg = s0 & 3;
  const unsigned short* pA = A + (size_t)(m0 + srow) * K_ + sg * 8;
  const unsigned short* pB = BT + (size_t)(n0 + srow) * K_ + sg * 8;
  const int laneG = ((l16 >> 1) * 8 + (((l16 & 1) * 4 + l4) ^ ((l16 >> 1) & 7))) * 8;

  f32x4 acc[8][4];
#pragma unroll
  for (int i = 0; i < 8; ++i)
#pragma unroll
    for (int j = 0; j < 4; ++j) acc[i][j] = (f32x4)(0.f);

  ushort8 aF[4], bF[4];

#define STG(dst, srcp, T, kh)                                                \
  do {                                                                       \
    const unsigned short* s_ = (srcp) + (T) * 64 + (kh) * 32;                \
    gload_lds16(s_, &(dst)[tid * 8]);                                        \
    gload_lds16(s_ + (size_t)128 * K_, &(dst)[(512 + tid) * 8]);             \
  } while (0)

#define LDA(mg, buf, ks)                                                     \
  do {                                                                       \
    _Pragma("unroll") for (int mf = 0; mf < 4; ++mf)                         \
      aF[mf] = *(const ushort8*)&a_lds[buf][ks]                              \
          [(wr * 512 + ((mg) * 4 + mf) * 64) * 8 + laneG];                   \
  } while (0)

#define LDB(buf, ks)                                                         \
  do {                                                                       \
    _Pragma("unroll") for (int nf = 0; nf < 4; ++nf)                         \
      bF[nf] = *(const ushort8*)&b_lds[buf][ks]                              \
          [(wc * 256 + nf * 64) * 8 + laneG];                                \
  } while (0)

#define MM(mg)                                                               \
  do {                                                                       \
    __builtin_amdgcn_s_setprio(1);                                           \
    _Pragma("unroll") for (int mf = 0; mf < 4; ++mf)                         \
      _Pragma("unroll") for (int nf = 0; nf < 4; ++nf)                       \
        acc[(mg) * 4 + mf][nf] = mfma16(aF[mf], bF[nf], acc[(mg) * 4 + mf][nf]); \
    __builtin_amdgcn_s_setprio(0);                                           \
  } while (0)

#define NOVM ((void)0)
#define VMC6 asm volatile("s_waitcnt vmcnt(6)" ::: "memory")
#define VMC0 asm volatile("s_waitcnt vmcnt(0)" ::: "memory")

#define PHASE(mg, ks, buf, LOADB, STAGE, VM)                                 \
  do {                                                                       \
    if (LOADB) { LDB(buf, ks); }                                             \
    LDA(mg, buf, ks);                                                        \
    STAGE;                                                                   \
    asm volatile("s_waitcnt lgkmcnt(0)" ::: "memory");                       \
    __builtin_amdgcn_sched_barrier(0);                                       \
    MM(mg);                                                                  \
    VM;                                                                      \
    __builtin_amdgcn_s_barrier();                                            \
  } while (0)

  STG(a_lds[0][0], pA, 0, 0);
  STG(b_lds[0][0], pB, 0, 0);
  STG(a_lds[0][1], pA, 0, 1);
  STG(b_lds[0][1], pB, 0, 1);
  STG(b_lds[1][0], pB, 1, 0);
  STG(a_lds[1][0], pA, 1, 0);
  STG(b_lds[1][1], pB, 1, 1);
  __builtin_amdgcn_sched_barrier(0);
  VMC6;
  __builtin_amdgcn_s_barrier();
  __builtin_amdgcn_sched_barrier(0);

#pragma unroll 1
  for (int i = 0; i < 15; ++i) {
    const int t1 = 2 * i + 1, t2 = 2 * i + 2, t3 = 2 * i + 3;
    PHASE(0, 0, 0, 1, STG(a_lds[1][1], pA, t1, 1), NOVM);
    PHASE(1, 0, 0, 0, STG(b_lds[0][0], pB, t2, 0), NOVM);
    PHASE(1, 1, 0, 1, STG(a_lds[0][0], pA, t2, 0), NOVM);
    PHASE(0, 1, 0, 0, STG(b_lds[0][1], pB, t2, 1), VMC6);
    PHASE(0, 0, 1, 1, STG(a_lds[0][1], pA, t2, 1), NOVM);
    PHASE(1, 0, 1, 0, STG(b_lds[1][0], pB, t3, 0), NOVM);
    PHASE(1, 1, 1, 1, STG(a_lds[1][0], pA, t3, 0), NOVM);
    PHASE(0, 1, 1, 0, STG(b_lds[1][1], pB, t3, 1), VMC6);
  }
  PHASE(0, 0, 0, 1, STG(a_lds[1][1], pA, 31, 1), NOVM);
  PHASE(1, 0, 0, 0, NOVM, NOVM);
  PHASE(1, 1, 0, 1, NOVM, NOVM);
  PHASE(0, 1, 0, 0, NOVM, VMC0);
  PHASE(0, 0, 1, 1, NOVM, NOVM);
  PHASE(1, 0, 1, 0, NOVM, NOVM);
  PHASE(1, 1, 1, 1, NOVM, NOVM);
  PHASE(0, 1, 1, 0, NOVM, NOVM);

#undef PHASE
#undef STG
#undef LDA
#undef LDB
#undef MM

#pragma unroll
  for (int mf = 0; mf < 8; ++mf) {
    const int mb = m0 + wr * 128 + mf * 16 + l4 * 4;
#pragma unroll
    for (int nf = 0; nf < 4; ++nf) {
      const int n = n0 + wc * 64 + nf * 16 + l16;
      const float bv = bias[n];
#pragma unroll
      for (int r = 0; r < 4; ++r) {
        const float v = acc[mf][nf][r] + bv;
        const int m = mb + r;
        if (EPI == 0) {
          const int b = m >> 11, s = m & 2047, h = n >> 7, d = n & 127;
          // pre-scale Q by log2(e)/sqrt(E) so attn uses exp2 directly
          ((unsigned short*)Cout)[(((size_t)(b * 16 + h) << 11) + s) * 128 + d] =
              f2bf(v * 0.031879358f);
        } else {
          ((float*)Cout)[(size_t)m * E_ + n] = v;
        }
      }
    }
  }
}

// ---------------- fused attention: 8-wave, 32x32 swapped-QK^T, in-register softmax --
// VERBATIM round-6/11 attn32 (HW-verified 162 us; conflict removal proved neutral in
// r12, so the simplest proven variant is kept).
// grid: (B*H, S/256); block 512 (8 waves x 32 q-rows). wgid%8 == bh%8 -> XCD affinity.
__global__ __launch_bounds__(512, 2) void attn32(const unsigned short* __restrict__ Qb,
                                                 const unsigned short* __restrict__ Kb,
                                                 const unsigned short* __restrict__ VT,
                                                 unsigned short* __restrict__ Ob) {
  const int bh = blockIdx.x, b = bh >> 4, h = bh & 15;
  const int tid = threadIdx.x, wv = tid >> 6, lane = tid & 63;
  const int l32 = lane & 31, hi = lane >> 5;
  const int s_glob = blockIdx.y * 256 + wv * 32 + l32;

  // K: [64 m][128 d], 16B granules XOR'd by (m&7); V: [128 d][64 m], XOR'd by (d&7).
  __shared__ __align__(16) unsigned short k_sm[2][64 * 128];
  __shared__ __align__(16) unsigned short v_sm[2][128 * 64];
  __shared__ float inv_lds[8][32];

  const unsigned short* Kh = Kb + (size_t)h * M_ * DH_;
  const unsigned short* Vh = VT + (size_t)h * DH_ * M_;

  // Q fragments (B-operand: col=s, k = d = dc*16 + hi*8 + j); pre-scaled in GEMM1.
  ushort8 qf[8];
  {
    const unsigned short* qrow = Qb + ((size_t)(b * 16 + h) * S_ + s_glob) * DH_ + hi * 8;
#pragma unroll
    for (int dc = 0; dc < 8; ++dc) qf[dc] = *(const ushort8*)(qrow + dc * 16);
  }

  f32x16 oacc[4];
#pragma unroll
  for (int dt = 0; dt < 4; ++dt) oacc[dt] = (f32x16)(0.f);
  float lsum = 0.f;

#define ASTAGE(buf, ch)                                                        \
  do {                                                                         \
    const int m0_ = (ch) << 6;                                                 \
    _Pragma("unroll") for (int j_ = 0; j_ < 2; ++j_) {                         \
      const int t_ = j_ * 512 + tid;                                           \
      const int m_ = t_ >> 4, p_ = t_ & 15;                                    \
      gload_lds16(Kh + (size_t)(m0_ + m_) * DH_ + ((p_ ^ (m_ & 7)) << 3),      \
                  &k_sm[buf][t_ * 8]);                                         \
    }                                                                          \
    _Pragma("unroll") for (int j_ = 0; j_ < 2; ++j_) {                         \
      const int t_ = j_ * 512 + tid;                                           \
      const int d_ = t_ >> 3, p_ = t_ & 7;                                     \
      gload_lds16(Vh + (size_t)d_ * M_ + m0_ + ((p_ ^ (d_ & 7)) << 3),         \
                  &v_sm[buf][t_ * 8]);                                         \
    }                                                                          \
  } while (0)

  int cur = 0;
  ASTAGE(0, 0);
  __syncthreads();

  for (int c = 0; c < 16; ++c) {
    if (c < 15) ASTAGE(cur ^ 1, c + 1);

    // ---- QK^T (swapped): sacc[mb] = K-rows (m) x Q-cols (s) ----
    f32x16 sacc[2];
    sacc[0] = (f32x16)(0.f);
    sacc[1] = (f32x16)(0.f);
#pragma unroll
    for (int mb = 0; mb < 2; ++mb) {
      const int m_ = mb * 32 + l32;
      const unsigned short* kr = &k_sm[cur][m_ * 128];
      __builtin_amdgcn_s_setprio(1);
#pragma unroll
      for (int dc = 0; dc < 8; ++dc) {
        ushort8 kf = *(const ushort8*)(kr + (((dc * 2 + hi) ^ (m_ & 7)) << 3));
        sacc[mb] = mfma32(kf, qf[dc], sacc[mb]);
      }
      __builtin_amdgcn_s_setprio(0);
    }

    // ---- in-register softmax (no max) + pack to PV A-frags + PV ----
#pragma unroll
    for (int mb = 0; mb < 2; ++mb) {
      float pe[16];
#pragma unroll
      for (int r = 0; r < 16; ++r) {
        pe[r] = exp2f_fast(sacc[mb][r]);
        lsum += pe[r];
      }
      ushort8 pa[2];
#pragma unroll
      for (int mk = 0; mk < 2; ++mk) {
        const int o = mk * 8;
        unsigned x0, x1, y0, y1;
        asm("v_cvt_pk_bf16_f32 %0, %1, %2" : "=v"(x0) : "v"(pe[o + 0]), "v"(pe[o + 1]));
        asm("v_cvt_pk_bf16_f32 %0, %1, %2" : "=v"(x1) : "v"(pe[o + 2]), "v"(pe[o + 3]));
        asm("v_cvt_pk_bf16_f32 %0, %1, %2" : "=v"(y0) : "v"(pe[o + 4]), "v"(pe[o + 5]));
        asm("v_cvt_pk_bf16_f32 %0, %1, %2" : "=v"(y1) : "v"(pe[o + 6]), "v"(pe[o + 7]));
        // exchange: dst.hi-lanes <-> src.lo-lanes; assembles k = m-consecutive bf16x8
        asm("v_permlane32_swap_b32 %0, %1" : "+v"(x0), "+v"(y0));
        asm("v_permlane32_swap_b32 %0, %1" : "+v"(x1), "+v"(y1));
        uint4v pw;
        pw[0] = x0; pw[1] = x1; pw[2] = y0; pw[3] = y1;
        pa[mk] = __builtin_bit_cast(ushort8, pw);
      }
#pragma unroll
      for (int dt = 0; dt < 4; ++dt) {
        const int d_ = dt * 32 + l32;
        const unsigned short* vr = &v_sm[cur][d_ * 64];
        __builtin_amdgcn_s_setprio(1);
#pragma unroll
        for (int mk = 0; mk < 2; ++mk) {
          const int gv = mb * 4 + mk * 2 + hi;
          ushort8 vf = *(const ushort8*)(vr + ((gv ^ (d_ & 7)) << 3));
          oacc[dt] = mfma32(pa[mk], vf, oacc[dt]);
        }
        __builtin_amdgcn_s_setprio(0);
      }
    }
    __syncthreads();
    cur ^= 1;
  }
#undef ASTAGE

  // ---- epilogue: denominator (lane + partner half), broadcast inv, store O ----
  float tot = lsum + __shfl_xor(lsum, 32, 64);
  if (hi == 0) inv_lds[wv][l32] = 1.0f / tot;
#pragma unroll
  for (int r = 0; r < 16; ++r) {
    const int srow = (r & 3) + 8 * (r >> 2) + 4 * hi;
    const float iv = inv_lds[wv][srow];
    unsigned short* orow =
        Ob + ((size_t)b * S_ + (size_t)(blockIdx.y * 256 + wv * 32 + srow)) * (H_ * DH_) +
        h * DH_ + l32;
#pragma unroll
    for (int dt = 0; dt < 4; ++dt) {
      const float val = oacc[dt][r] * iv;
      unsigned u;
      asm("v_cvt_pk_bf16_f32 %0, %1, %2" : "=v"(u) : "v"(val), "v"(val));
      orow[dt * 32] = (unsigned short)u;
    }
  }
}

// ---------------- launcher ----------------

extern "C" void kernel_launch(void* const* d_in, const int* in_sizes, int n_in,
                              void* d_out, int out_size, void* d_ws, size_t ws_size,
                              hipStream_t stream) {
  const float* X   = (const float*)d_in[0];
  const float* Wq  = (const float*)d_in[1];
  const float* bq  = (const float*)d_in[2];
  const float* Kp  = (const float*)d_in[3];
  const float* Cal = (const float*)d_in[4];
  const float* V   = (const float*)d_in[5];
  const float* Wd  = (const float*)d_in[6];
  const float* bd  = (const float*)d_in[7];

  char* ws = (char*)d_ws;
  unsigned short* Xbf = (unsigned short*)(ws + 0);          // 67108864 B (reused as Ob)
  unsigned short* Ob  = Xbf;                                 // alias: X dead after GEMM1
  unsigned short* Qb  = (unsigned short*)(ws + 67108864);   // 67108864 B
  unsigned short* WqT = (unsigned short*)(ws + 134217728);  // 8388608 B
  unsigned short* WdT = (unsigned short*)(ws + 142606336);  // 8388608 B
  unsigned short* Kb  = (unsigned short*)(ws + 150994944);  // 4194304 B
  unsigned short* VT  = (unsigned short*)(ws + 155189248);  // 4194304 B

  // conversions
  cvt_bf16<<<2048, 256, 0, stream>>>(X, Xbf, (B_ * S_ * E_) / 4);
  addcvt_bf16<<<1024, 256, 0, stream>>>(Kp, Cal, Kb, (H_ * M_ * DH_) / 4);
  transpose_cvt<<<dim3(E_ / 64, E_ / 64, 1), 256, 0, stream>>>(Wq, WqT, E_, H_ * DH_);
  transpose_cvt<<<dim3(E_ / 64, E_ / 64, 1), 256, 0, stream>>>(Wd, WdT, H_ * DH_, E_);
  transpose_cvt<<<dim3(DH_ / 64, M_ / 64, H_), 256, 0, stream>>>(V, VT, M_, DH_);

  // Q projection: (B*S, E) x (E, H*Dh) -> Q bf16 (B,H,S,Dh), pre-scaled
  gemm8p<0><<<dim3(512), 512, 0, stream>>>(Xbf, WqT, bq, Qb);

  // fused attention -> Ob bf16 (B,S,H*Dh)
  attn32<<<dim3(B_ * H_, S_ / 256), 512, 0, stream>>>(Qb, Kb, VT, Ob);

  // dehead: (B*S, H*Dh) x (H*Dh, E) -> f32 out
  gemm8p<1><<<dim3(512), 512, 0, stream>>>(Ob, WdT, bd, (float*)d_out);
}